// Round 5
// baseline (539.252 us; speedup 1.0000x reference)
//
#include <hip/hip_runtime.h>

#define B_SZ 2
#define T_SZ 4096

typedef unsigned short u16;
typedef __attribute__((ext_vector_type(8))) short short8;
typedef __attribute__((ext_vector_type(4))) float f32x4;
typedef __attribute__((ext_vector_type(4))) unsigned short u16x4;

#define CEXP 0.51006973f   // (8^-0.5) * log2(e), folded into Q projection

__device__ __forceinline__ u16 f2bf(float f) {            // round-to-nearest-even
    unsigned int u;
    __builtin_memcpy(&u, &f, 4);
    u = (u + 0x7fffu + ((u >> 16) & 1u)) >> 16;
    return (u16)u;
}
__device__ __forceinline__ unsigned int rbits(float f) {  // bits + half-up round offset
    unsigned int u;
    __builtin_memcpy(&u, &f, 4);
    return u + 0x8000u;
}
__device__ __forceinline__ f32x4 mfma16(short8 a, short8 b, f32x4 c) {
    return __builtin_amdgcn_mfma_f32_16x16x32_bf16(a, b, c, 0, 0, 0);
}

// ---------- persistent grid barrier ----------
// Self-resetting sense-reversal: cnt returns to 0 before gen bumps, so the BSS
// zero-init state is re-established for every graph replay (no host memset).
// Residency of all 512 blocks is guaranteed by __launch_bounds__(512,4) (VGPR<=128
// -> 4 waves/EU) + LDS 55296 B (2 blocks/CU) -> capacity == grid size.
struct GBar { unsigned int cnt; unsigned int p0[15]; unsigned int gen; unsigned int p1[15]; };
__device__ GBar g_bar[3];
#define NBLK 512

__device__ __forceinline__ void gridbar(int i) {
    __syncthreads();
    if (threadIdx.x == 0) {
        unsigned int g = __hip_atomic_load(&g_bar[i].gen, __ATOMIC_ACQUIRE, __HIP_MEMORY_SCOPE_AGENT);
        unsigned int a = __hip_atomic_fetch_add(&g_bar[i].cnt, 1u, __ATOMIC_ACQ_REL, __HIP_MEMORY_SCOPE_AGENT);
        if (a == NBLK - 1u) {
            __hip_atomic_store(&g_bar[i].cnt, 0u, __ATOMIC_RELAXED, __HIP_MEMORY_SCOPE_AGENT);
            __hip_atomic_fetch_add(&g_bar[i].gen, 1u, __ATOMIC_RELEASE, __HIP_MEMORY_SCOPE_AGENT);
        } else {
            while (__hip_atomic_load(&g_bar[i].gen, __ATOMIC_ACQUIRE, __HIP_MEMORY_SCOPE_AGENT) == g)
                __builtin_amdgcn_s_sleep(2);
        }
    }
    __syncthreads();
}

// ---------- 512-thread GEMM phase: D = A[M,512] x Bt[N,512]^T, TM=128 TN=256 BK=64 ----------
// 8 waves: mo=(wave&1)*64, no=(wave>>1)*64; per-wave 4x4 16x16 fragments (r1-validated math).
// Loads issued pre-barrier (latency hidden under other block's MFMA); no cross-iter
// reg prefetch -> peak VGPR ~116 (fits the 128 cap, no spill).
// MODE 0 (out): bias add -> out[t][512] float4.
// MODE 1 (qk):  -> Qh[b,h,t,64]*CEXP / Kh, u16x4.
// MODE 2 (v):   -> Vb[b,h,kt,64d,64k], u16x4 along k64.
template <typename OutT, int MODE, bool AF32, bool BF32>
__device__ void gemm512(int m0, int n0, const void* __restrict__ Ap, const void* __restrict__ Bp,
                        const float* __restrict__ bias, OutT* __restrict__ C,
                        OutT* __restrict__ C2, u16* smem) {
    const int K = 512;
    u16* As = smem;                 // [128][72]
    u16* Bs = smem + 128 * 72;      // [256][72]
    int tid = threadIdx.x;
    int wave = tid >> 6, lane = tid & 63, l16 = lane & 15, q = lane >> 4;
    int mo = (wave & 1) * 64, no = (wave >> 1) * 64;

    f32x4 acc[4][4];
#pragma unroll
    for (int i = 0; i < 4; ++i)
#pragma unroll
        for (int j = 0; j < 4; ++j) acc[i][j] = (f32x4){0.f, 0.f, 0.f, 0.f};

    const float* Af = (const float*)Ap; const u16* Ab = (const u16*)Ap;
    const float* Bf = (const float*)Bp; const u16* Bb = (const u16*)Bp;

#pragma unroll 1
    for (int k0 = 0; k0 < K; k0 += 64) {
        float4 raf[AF32 ? 4 : 1]; short8 rab[AF32 ? 1 : 2];
        float4 rbf[BF32 ? 8 : 1]; short8 rbb[BF32 ? 1 : 4];
        if constexpr (AF32) {
#pragma unroll
            for (int jj = 0; jj < 4; ++jj) {
                int id = tid + 512 * jj;
                raf[jj] = *(const float4*)(Af + (size_t)(m0 + (id >> 4)) * K + k0 + (id & 15) * 4);
            }
        } else {
#pragma unroll
            for (int jj = 0; jj < 2; ++jj) {
                int id = tid + 512 * jj;
                rab[jj] = *(const short8*)(Ab + (size_t)(m0 + (id >> 3)) * K + k0 + (id & 7) * 8);
            }
        }
        if constexpr (BF32) {
#pragma unroll
            for (int jj = 0; jj < 8; ++jj) {
                int id = tid + 512 * jj;
                rbf[jj] = *(const float4*)(Bf + (size_t)(n0 + (id >> 4)) * K + k0 + (id & 15) * 4);
            }
        } else {
#pragma unroll
            for (int jj = 0; jj < 4; ++jj) {
                int id = tid + 512 * jj;
                rbb[jj] = *(const short8*)(Bb + (size_t)(n0 + (id >> 3)) * K + k0 + (id & 7) * 8);
            }
        }
        __builtin_amdgcn_sched_barrier(0);               // keep loads issued pre-barrier
        __syncthreads();                                 // previous tile fully consumed
        if constexpr (AF32) {
#pragma unroll
            for (int jj = 0; jj < 4; ++jj) {
                int id = tid + 512 * jj;
                u16x4 w = { f2bf(raf[jj].x), f2bf(raf[jj].y), f2bf(raf[jj].z), f2bf(raf[jj].w) };
                *(u16x4*)(&As[(id >> 4) * 72 + (id & 15) * 4]) = w;
            }
        } else {
#pragma unroll
            for (int jj = 0; jj < 2; ++jj) {
                int id = tid + 512 * jj;
                *(short8*)(&As[(id >> 3) * 72 + (id & 7) * 8]) = rab[jj];
            }
        }
        if constexpr (BF32) {
#pragma unroll
            for (int jj = 0; jj < 8; ++jj) {
                int id = tid + 512 * jj;
                u16x4 w = { f2bf(rbf[jj].x), f2bf(rbf[jj].y), f2bf(rbf[jj].z), f2bf(rbf[jj].w) };
                *(u16x4*)(&Bs[(id >> 4) * 72 + (id & 15) * 4]) = w;
            }
        } else {
#pragma unroll
            for (int jj = 0; jj < 4; ++jj) {
                int id = tid + 512 * jj;
                *(short8*)(&Bs[(id >> 3) * 72 + (id & 7) * 8]) = rbb[jj];
            }
        }
        __syncthreads();

#pragma unroll
        for (int kk = 0; kk < 2; ++kk) {
            short8 af[4], bf[4];
#pragma unroll
            for (int i = 0; i < 4; ++i)
                af[i] = *(const short8*)(&As[(mo + i * 16 + l16) * 72 + kk * 32 + q * 8]);
#pragma unroll
            for (int j = 0; j < 4; ++j)
                bf[j] = *(const short8*)(&Bs[(no + j * 16 + l16) * 72 + kk * 32 + q * 8]);
#pragma unroll
            for (int i = 0; i < 4; ++i)
#pragma unroll
                for (int j = 0; j < 4; ++j) acc[i][j] = mfma16(af[i], bf[j], acc[i][j]);
        }
    }

    // epilogue: Mrow = m0+mo+i*16+q*4+r (r consecutive), Ncol = n0+no+j*16+l16
#pragma unroll
    for (int i = 0; i < 4; ++i) {
        int mb = m0 + mo + i * 16 + q * 4;
#pragma unroll
        for (int j = 0; j < 4; ++j) {
            int nc = n0 + no + j * 16 + l16;
            if constexpr (MODE == 0) {
                float4 bb = *(const float4*)(bias + mb);
                float4 w = { acc[i][j][0] + bb.x, acc[i][j][1] + bb.y,
                             acc[i][j][2] + bb.z, acc[i][j][3] + bb.w };
                *(float4*)(&C[(size_t)nc * 512 + mb]) = w;
            } else if constexpr (MODE == 1) {
                int b = nc >> 12, t = nc & 4095;
                int h = (mb & 511) >> 6, d = mb & 63;
                size_t addr = ((size_t)((b * 8 + h) * 4096 + t)) * 64 + d;
                if (mb < 512) {
                    u16x4 w = { f2bf(acc[i][j][0] * CEXP), f2bf(acc[i][j][1] * CEXP),
                                f2bf(acc[i][j][2] * CEXP), f2bf(acc[i][j][3] * CEXP) };
                    *(u16x4*)(&C[addr]) = w;
                } else {
                    u16x4 w = { f2bf(acc[i][j][0]), f2bf(acc[i][j][1]),
                                f2bf(acc[i][j][2]), f2bf(acc[i][j][3]) };
                    *(u16x4*)(&C2[addr]) = w;
                }
            } else {                                           // v: M=token, N=ch
                int b = mb >> 12, t = mb & 4095;
                int kt = t >> 6, k64 = t & 63;
                int h = nc >> 6, d = nc & 63;
                size_t addr = ((((size_t)(b * 8 + h) * 64 + kt) * 64 + d) << 6) + k64;
                u16x4 w = { f2bf(acc[i][j][0]), f2bf(acc[i][j][1]),
                            f2bf(acc[i][j][2]), f2bf(acc[i][j][3]) };
                *(u16x4*)(&C[addr]) = w;
            }
        }
    }
}

// ---------- flash phase (r4-validated body: K-swizzle + setprio) ----------
__device__ void flash_dev(int bid, const u16* __restrict__ Qh, const u16* __restrict__ Kh,
                          const u16* __restrict__ Vb, u16* __restrict__ o, u16* sm) {
    int h = bid & 7, qt = (bid >> 3) & 31, b = bid >> 8;
    int tid = threadIdx.x;
    int wave = tid >> 6, lane = tid & 63, l16 = lane & 15, q = lane >> 4;
    int ks = wave >> 2, w4 = wave & 3;
    int t256 = tid & 255;

    u16* Kt = sm + ks * 8704;                              // K[64*64] + V[64*72] per ks
    u16* Vt = Kt + 64 * 64;

    int head = b * 8 + h;
    short8 qf[2][2];
#pragma unroll
    for (int g = 0; g < 2; ++g) {
        const u16* qp = Qh + ((size_t)head * 4096 + qt * 128 + g * 64 + w4 * 16 + l16) * 64 + q * 8;
        qf[g][0] = *(const short8*)(qp);
        qf[g][1] = *(const short8*)(qp + 32);
    }

    const u16* kb = Kh + (size_t)head * 4096 * 64;
    const u16* vb = Vb + (size_t)head * 4096 * 64;

    int r0 = t256 >> 3, g0 = t256 & 7;
    int sr = (r0 & 3) | (((r0 >> 3) & 1) << 2);            // s(row), same for r0 and r0+32
    u16* kw0 = &Kt[r0 * 64 + ((g0 ^ sr) << 3)];
    u16* kw1 = kw0 + 32 * 64;
    u16* vw0 = &Vt[r0 * 72 + g0 * 8];
    u16* vw1 = vw0 + 32 * 72;

    f32x4 oacc[2][4];
#pragma unroll
    for (int g = 0; g < 2; ++g)
#pragma unroll
        for (int c = 0; c < 4; ++c) oacc[g][c] = (f32x4){0.f, 0.f, 0.f, 0.f};
    f32x4 lacc[2];
    lacc[0] = (f32x4){0.f, 0.f, 0.f, 0.f};
    lacc[1] = (f32x4){0.f, 0.f, 0.f, 0.f};
    const short8 ones = { 0x3F80, 0x3F80, 0x3F80, 0x3F80, 0x3F80, 0x3F80, 0x3F80, 0x3F80 };
    int pi0 = (l16 >> 2) * 8 + (l16 & 3);
    int sq = l16 & 7;

    size_t off0 = (size_t)(ks * 32 + (qt & 31)) * 4096;
    short8 rk0 = *(const short8*)(kb + off0 + t256 * 8);
    short8 rk1 = *(const short8*)(kb + off0 + t256 * 8 + 2048);
    short8 rv0 = *(const short8*)(vb + off0 + t256 * 8);
    short8 rv1 = *(const short8*)(vb + off0 + t256 * 8 + 2048);

#pragma unroll 1
    for (int it = 0; it < 32; ++it) {
        __syncthreads();
        *(short8*)kw0 = rk0;
        *(short8*)kw1 = rk1;
        *(short8*)vw0 = rv0;
        *(short8*)vw1 = rv1;
        __syncthreads();

        size_t offn = (size_t)(ks * 32 + ((qt + it + 1) & 31)) * 4096;
        rk0 = *(const short8*)(kb + offn + t256 * 8);
        rk1 = *(const short8*)(kb + offn + t256 * 8 + 2048);
        rv0 = *(const short8*)(vb + offn + t256 * 8);
        rv1 = *(const short8*)(vb + offn + t256 * 8 + 2048);
        __builtin_amdgcn_sched_barrier(0);

        __builtin_amdgcn_s_setprio(1);
#pragma unroll
        for (int kk = 0; kk < 2; ++kk) {
            const u16* ka = &Kt[(kk * 32 + pi0) * 64];
            short8 A00 = *(const short8*)(ka + ((q ^ sq) << 3));
            short8 A01 = *(const short8*)(ka + (((4 | q) ^ sq) << 3));
            short8 A10 = *(const short8*)(ka + 4 * 64 + ((q ^ sq) << 3));
            short8 A11 = *(const short8*)(ka + 4 * 64 + (((4 | q) ^ sq) << 3));
            short8 vfc[4];
#pragma unroll
            for (int c = 0; c < 4; ++c)
                vfc[c] = *(const short8*)(&Vt[(c * 16 + l16) * 72 + kk * 32 + q * 8]);

#pragma unroll
            for (int g = 0; g < 2; ++g) {
                f32x4 s0 = (f32x4){0.f, 0.f, 0.f, 0.f};
                f32x4 s1 = (f32x4){0.f, 0.f, 0.f, 0.f};
                s0 = mfma16(A00, qf[g][0], s0); s0 = mfma16(A01, qf[g][1], s0);
                s1 = mfma16(A10, qf[g][0], s1); s1 = mfma16(A11, qf[g][1], s1);

                uint4 pd;
                pd.x = __builtin_amdgcn_perm(rbits(__builtin_amdgcn_exp2f(s0[1])),
                                             rbits(__builtin_amdgcn_exp2f(s0[0])), 0x07060302u);
                pd.y = __builtin_amdgcn_perm(rbits(__builtin_amdgcn_exp2f(s0[3])),
                                             rbits(__builtin_amdgcn_exp2f(s0[2])), 0x07060302u);
                pd.z = __builtin_amdgcn_perm(rbits(__builtin_amdgcn_exp2f(s1[1])),
                                             rbits(__builtin_amdgcn_exp2f(s1[0])), 0x07060302u);
                pd.w = __builtin_amdgcn_perm(rbits(__builtin_amdgcn_exp2f(s1[3])),
                                             rbits(__builtin_amdgcn_exp2f(s1[2])), 0x07060302u);
                short8 pf;
                __builtin_memcpy(&pf, &pd, 16);

                lacc[g] = mfma16(ones, pf, lacc[g]);
#pragma unroll
                for (int c = 0; c < 4; ++c)
                    oacc[g][c] = mfma16(vfc[c], pf, oacc[g][c]);
            }
        }
        __builtin_amdgcn_s_setprio(0);
    }

    __syncthreads();
    float* red = (float*)sm;
    if (ks == 1) {
        float* rp = red + ((w4 * 64 + lane) * 37);
#pragma unroll
        for (int g = 0; g < 2; ++g)
#pragma unroll
            for (int c = 0; c < 4; ++c)
#pragma unroll
                for (int r = 0; r < 4; ++r) rp[g * 16 + c * 4 + r] = oacc[g][c][r];
        rp[32] = lacc[0][0];
        rp[33] = lacc[1][0];
    }
    __syncthreads();
    if (ks == 0) {
        const float* rp = red + ((w4 * 64 + lane) * 37);
#pragma unroll
        for (int g = 0; g < 2; ++g) {
#pragma unroll
            for (int c = 0; c < 4; ++c)
#pragma unroll
                for (int r = 0; r < 4; ++r) oacc[g][c][r] += rp[g * 16 + c * 4 + r];
            float inv = 1.f / (lacc[g][0] + rp[32 + g]);
            u16* ob = o + (size_t)(b * T_SZ + qt * 128 + g * 64 + w4 * 16 + l16) * 512 + h * 64 + q * 4;
#pragma unroll
            for (int c = 0; c < 4; ++c) {
                u16x4 w = { f2bf(oacc[g][c][0] * inv), f2bf(oacc[g][c][1] * inv),
                            f2bf(oacc[g][c][2] * inv), f2bf(oacc[g][c][3] * inv) };
                *(u16x4*)(ob + c * 16) = w;
            }
        }
    }
}

// ---------- fused single-dispatch kernel ----------
// 512 blocks x 512 threads, all grid-resident (see gridbar note).
// P1 prep (128 blocks, 2x256-thr halves) | P2 qkv (384 blocks) | P3 flash (512) | P4 out (128).
__global__ __launch_bounds__(512, 4) void k_fused(
    const float* __restrict__ x, const float* __restrict__ cond,
    const float* __restrict__ Wqk, const float* __restrict__ Wv,
    const float* __restrict__ Wu, const float* __restrict__ bu, float* __restrict__ out,
    u16* __restrict__ Qh, u16* __restrict__ Kh, u16* __restrict__ Vb, u16* __restrict__ at,
    u16* __restrict__ Wqk_t, u16* __restrict__ Wv_t, u16* __restrict__ Wu_t) {
    __shared__ __align__(16) u16 smem[27648];              // 55296 B
    int bid = blockIdx.x, tid = threadIdx.x;

    // ---- P1: weight transposes (validated k_prep, two 256-thread halves per block) ----
    if (bid < 128) {
        int half = tid >> 8, t256 = tid & 255;
        int ti = bid * 2 + half;
        u16 (*T)[72] = (u16(*)[72])(smem + half * 4608);
        const float* src; u16* dst; int N, tt;
        if (ti < 128)      { src = Wqk; dst = Wqk_t; N = 1024; tt = ti; }
        else if (ti < 192) { src = Wv;  dst = Wv_t;  N = 512;  tt = ti - 128; }
        else               { src = Wu;  dst = Wu_t;  N = 512;  tt = ti - 192; }
        int nt = N >> 6;
        int bi = tt / nt, bj = tt - bi * nt;
        int kb = bi * 64, nb = bj * 64;
        int r = t256 >> 2, c4 = (t256 & 3) * 16;
#pragma unroll
        for (int jj = 0; jj < 4; ++jj) {
            float4 v = *(const float4*)(src + (size_t)(kb + r) * N + nb + c4 + jj * 4);
            u16x4 w = { f2bf(v.x), f2bf(v.y), f2bf(v.z), f2bf(v.w) };
            *(u16x4*)(&T[r][c4 + jj * 4]) = w;
        }
        __syncthreads();
#pragma unroll
        for (int jj = 0; jj < 4; ++jj) {
            int c = c4 + jj * 4;
            u16x4 w = { T[c][r], T[c + 1][r], T[c + 2][r], T[c + 3][r] };
            *(u16x4*)(dst + (size_t)(nb + r) * 512 + kb + c) = w;
        }
    }
    gridbar(0);

    // ---- P2: qk-proj (256 blocks) + v-proj (128 blocks) ----
    if (bid < 256) {
        int bx = bid >> 5, by = bid & 31;                  // stripe-sharers differ by 32 == 0 mod 8
        gemm512<u16, 1, false, true>(bx * 128, by * 256, Wqk_t, cond, nullptr, Qh, Kh, smem);
    } else if (bid < 384) {
        int id2 = bid - 256;
        int m = id2 & 63, n = id2 >> 6;                    // x-stripe-sharers differ by 64 == 0 mod 8
        gemm512<u16, 2, true, false>(m * 128, n * 256, x, Wv_t, nullptr, Vb, nullptr, smem);
    }
    gridbar(1);

    // ---- P3: flash attention (all 512 blocks) ----
    flash_dev(bid, Qh, Kh, Vb, at, smem);
    gridbar(2);

    // ---- P4: out-proj (128 blocks) ----
    if (bid < 128) {
        int bx = bid >> 5, by = bid & 31;
        gemm512<float, 0, false, false>(bx * 128, by * 256, Wu_t, at, bu, out, nullptr, smem);
    }
}

extern "C" void kernel_launch(void* const* d_in, const int* in_sizes, int n_in,
                              void* d_out, int out_size, void* d_ws, size_t ws_size,
                              hipStream_t stream) {
    const float* x    = (const float*)d_in[0];   // [2,4096,512] f32
    const float* cond = (const float*)d_in[1];   // [2,4096,512] f32
    const float* Wqk  = (const float*)d_in[2];   // [512,1024]   f32
    const float* Wv   = (const float*)d_in[3];   // [512,512]    f32
    const float* Wu   = (const float*)d_in[4];   // [512,512]    f32
    const float* bu   = (const float*)d_in[5];   // [512]        f32
    float* out = (float*)d_out;                  // [2,4096,512] f32

    const size_t MT = (size_t)B_SZ * T_SZ;       // 8192
    u16* qh_ws = (u16*)d_ws;                     // [16 heads,4096,64]  8 MB (Q pre-scaled)
    u16* kh_ws = qh_ws + MT * 512;               // [16 heads,4096,64]  8 MB
    u16* vb_ws = kh_ws + MT * 512;               // [16,64kt,64d,64k]   8 MB
    u16* at_ws = vb_ws + MT * 512;               // [8192,512]          8 MB
    u16* Wqk_t = at_ws + MT * 512;               // [1024,512]          1 MB
    u16* Wv_t  = Wqk_t + (size_t)1024 * 512;     // [512,512]         0.5 MB
    u16* Wu_t  = Wv_t + (size_t)512 * 512;       // [512,512]         0.5 MB

    k_fused<<<512, 512, 0, stream>>>(x, cond, Wqk, Wv, Wu, bu, out,
                                     qh_ws, kh_ws, vb_ws, at_ws, Wqk_t, Wv_t, Wu_t);
}

// Round 7
// 204.750 us; speedup vs baseline: 2.6337x; 2.6337x over previous
//
#include <hip/hip_runtime.h>

#define B_SZ 2
#define T_SZ 4096

typedef unsigned short u16;
typedef __attribute__((ext_vector_type(8))) short short8;
typedef __attribute__((ext_vector_type(4))) float f32x4;
typedef __attribute__((ext_vector_type(4))) unsigned short u16x4;

#define CEXP 0.51006973f   // (8^-0.5) * log2(e), folded into Q projection

__device__ __forceinline__ u16 f2bf(float f) {            // round-to-nearest-even
    unsigned int u;
    __builtin_memcpy(&u, &f, 4);
    u = (u + 0x7fffu + ((u >> 16) & 1u)) >> 16;
    return (u16)u;
}
__device__ __forceinline__ unsigned int rbits(float f) {  // bits + half-up round offset
    unsigned int u;
    __builtin_memcpy(&u, &f, 4);
    return u + 0x8000u;
}
__device__ __forceinline__ f32x4 mfma16(short8 a, short8 b, f32x4 c) {
    return __builtin_amdgcn_mfma_f32_16x16x32_bf16(a, b, c, 0, 0, 0);
}

// ---------- prep: LDS-tiled weight transposes ONLY (r1-exact) ----------
__global__ void k_prep(const float* __restrict__ Wqk, const float* __restrict__ Wv,
                       const float* __restrict__ Wu, u16* __restrict__ Wqk_t,
                       u16* __restrict__ Wv_t, u16* __restrict__ Wu_t) {
    int blk = blockIdx.x, tid = threadIdx.x;
    __shared__ u16 T[64][72];
    const float* src; u16* dst; int N, ti;
    if (blk < 128)      { src = Wqk; dst = Wqk_t; N = 1024; ti = blk; }
    else if (blk < 192) { src = Wv;  dst = Wv_t;  N = 512;  ti = blk - 128; }
    else                { src = Wu;  dst = Wu_t;  N = 512;  ti = blk - 192; }
    int nt = N >> 6;
    int bi = ti / nt, bj = ti - bi * nt;
    int kb = bi * 64, nb = bj * 64;
    int r = tid >> 2, c4 = (tid & 3) * 16;
#pragma unroll
    for (int jj = 0; jj < 4; ++jj) {
        float4 v = *(const float4*)(src + (size_t)(kb + r) * N + nb + c4 + jj * 4);
        u16x4 w = { f2bf(v.x), f2bf(v.y), f2bf(v.z), f2bf(v.w) };
        *(u16x4*)(&T[r][c4 + jj * 4]) = w;
    }
    __syncthreads();
#pragma unroll
    for (int jj = 0; jj < 4; ++jj) {
        int c = c4 + jj * 4;
        u16x4 w = { T[c][r], T[c + 1][r], T[c + 2][r], T[c + 3][r] };
        *(u16x4*)(dst + (size_t)(nb + r) * 512 + kb + c) = w;
    }
}

// ---------- shared GEMM body (r1-exact): D = A[M,512] x Bt[N,512]^T, BK=64 ----------
template <typename OutT, int MODE, bool AF32, bool BF32, int TM, int TN>
__device__ __forceinline__ void gemm_body(int m0, int n0,
                                          const void* __restrict__ Ap, const void* __restrict__ Bp,
                                          const float* __restrict__ bias, OutT* __restrict__ C,
                                          OutT* __restrict__ C2, u16* As, u16* Bs) {
    const int K = 512;
    constexpr int BK = 64;
    constexpr int MI = TM / 32, NJ = TN / 32;
    constexpr int NAF = TM / 16, NAB = TM / 32;
    constexpr int NBF = TN / 16, NBB = TN / 32;
    int tid = threadIdx.x;
    int wave = tid >> 6, lane = tid & 63, l16 = lane & 15, q = lane >> 4;
    int mo = (wave & 1) * (TM / 2), no = (wave >> 1) * (TN / 2);

    f32x4 acc[MI][NJ];
#pragma unroll
    for (int i = 0; i < MI; ++i)
#pragma unroll
        for (int j = 0; j < NJ; ++j) acc[i][j] = (f32x4){0.f, 0.f, 0.f, 0.f};

    const float* Af = (const float*)Ap; const u16* Ab = (const u16*)Ap;
    const float* Bf = (const float*)Bp; const u16* Bb = (const u16*)Bp;

    const float* apf[NAF > 0 ? NAF : 1]; const u16* apb[NAB > 0 ? NAB : 1];
    const float* bpf[NBF > 0 ? NBF : 1]; const u16* bpb[NBB > 0 ? NBB : 1];
    float4 raf[NAF > 0 ? NAF : 1], rbf[NBF > 0 ? NBF : 1];
    short8 rab[NAB > 0 ? NAB : 1], rbb[NBB > 0 ? NBB : 1];

    if constexpr (AF32) {
#pragma unroll
        for (int jj = 0; jj < NAF; ++jj) {
            int id = tid + 256 * jj;
            apf[jj] = Af + (size_t)(m0 + (id >> 4)) * K + (id & 15) * 4;
            raf[jj] = *(const float4*)(apf[jj]);
        }
    } else {
#pragma unroll
        for (int jj = 0; jj < NAB; ++jj) {
            int id = tid + 256 * jj;
            apb[jj] = Ab + (size_t)(m0 + (id >> 3)) * K + (id & 7) * 8;
            rab[jj] = *(const short8*)(apb[jj]);
        }
    }
    if constexpr (BF32) {
#pragma unroll
        for (int jj = 0; jj < NBF; ++jj) {
            int id = tid + 256 * jj;
            bpf[jj] = Bf + (size_t)(n0 + (id >> 4)) * K + (id & 15) * 4;
            rbf[jj] = *(const float4*)(bpf[jj]);
        }
    } else {
#pragma unroll
        for (int jj = 0; jj < NBB; ++jj) {
            int id = tid + 256 * jj;
            bpb[jj] = Bb + (size_t)(n0 + (id >> 3)) * K + (id & 7) * 8;
            rbb[jj] = *(const short8*)(bpb[jj]);
        }
    }

#pragma unroll 1
    for (int k0 = 0; k0 < K; k0 += BK) {
        __syncthreads();
        if constexpr (AF32) {
#pragma unroll
            for (int jj = 0; jj < NAF; ++jj) {
                int id = tid + 256 * jj;
                u16x4 w = { f2bf(raf[jj].x), f2bf(raf[jj].y), f2bf(raf[jj].z), f2bf(raf[jj].w) };
                *(u16x4*)(&As[(id >> 4) * 72 + (id & 15) * 4]) = w;
            }
        } else {
#pragma unroll
            for (int jj = 0; jj < NAB; ++jj) {
                int id = tid + 256 * jj;
                *(short8*)(&As[(id >> 3) * 72 + (id & 7) * 8]) = rab[jj];
            }
        }
        if constexpr (BF32) {
#pragma unroll
            for (int jj = 0; jj < NBF; ++jj) {
                int id = tid + 256 * jj;
                u16x4 w = { f2bf(rbf[jj].x), f2bf(rbf[jj].y), f2bf(rbf[jj].z), f2bf(rbf[jj].w) };
                *(u16x4*)(&Bs[(id >> 4) * 72 + (id & 15) * 4]) = w;
            }
        } else {
#pragma unroll
            for (int jj = 0; jj < NBB; ++jj) {
                int id = tid + 256 * jj;
                *(short8*)(&Bs[(id >> 3) * 72 + (id & 7) * 8]) = rbb[jj];
            }
        }
        __syncthreads();

        int kadv = (k0 + BK < K) ? BK : 0;
        if constexpr (AF32) {
#pragma unroll
            for (int jj = 0; jj < NAF; ++jj) { apf[jj] += kadv; raf[jj] = *(const float4*)(apf[jj]); }
        } else {
#pragma unroll
            for (int jj = 0; jj < NAB; ++jj) { apb[jj] += kadv; rab[jj] = *(const short8*)(apb[jj]); }
        }
        if constexpr (BF32) {
#pragma unroll
            for (int jj = 0; jj < NBF; ++jj) { bpf[jj] += kadv; rbf[jj] = *(const float4*)(bpf[jj]); }
        } else {
#pragma unroll
            for (int jj = 0; jj < NBB; ++jj) { bpb[jj] += kadv; rbb[jj] = *(const short8*)(bpb[jj]); }
        }
        __builtin_amdgcn_sched_barrier(0);

#pragma unroll
        for (int kk = 0; kk < 2; ++kk) {
            short8 af[MI], bf[NJ];
#pragma unroll
            for (int i = 0; i < MI; ++i)
                af[i] = *(const short8*)(&As[(mo + i * 16 + l16) * 72 + kk * 32 + q * 8]);
#pragma unroll
            for (int j = 0; j < NJ; ++j)
                bf[j] = *(const short8*)(&Bs[(no + j * 16 + l16) * 72 + kk * 32 + q * 8]);
#pragma unroll
            for (int i = 0; i < MI; ++i)
#pragma unroll
                for (int j = 0; j < NJ; ++j) acc[i][j] = mfma16(af[i], bf[j], acc[i][j]);
        }
    }

    // epilogue: Mrow = m0+mo+i*16+q*4+r (r consecutive), Ncol = n0+no+j*16+l16
#pragma unroll
    for (int i = 0; i < MI; ++i) {
        int mb = m0 + mo + i * 16 + q * 4;
#pragma unroll
        for (int j = 0; j < NJ; ++j) {
            int nc = n0 + no + j * 16 + l16;
            if constexpr (MODE == 0) {
                float4 bb = *(const float4*)(bias + mb);
                float4 w = { acc[i][j][0] + bb.x, acc[i][j][1] + bb.y,
                             acc[i][j][2] + bb.z, acc[i][j][3] + bb.w };
                *(float4*)(&C[(size_t)nc * 512 + mb]) = w;
            } else if constexpr (MODE == 1) {
                int b = nc >> 12, t = nc & 4095;
                int h = (mb & 511) >> 6, d = mb & 63;
                size_t addr = ((size_t)((b * 8 + h) * 4096 + t)) * 64 + d;
                if (mb < 512) {
                    u16x4 w = { f2bf(acc[i][j][0] * CEXP), f2bf(acc[i][j][1] * CEXP),
                                f2bf(acc[i][j][2] * CEXP), f2bf(acc[i][j][3] * CEXP) };
                    *(u16x4*)(&C[addr]) = w;
                } else {
                    u16x4 w = { f2bf(acc[i][j][0]), f2bf(acc[i][j][1]),
                                f2bf(acc[i][j][2]), f2bf(acc[i][j][3]) };
                    *(u16x4*)(&C2[addr]) = w;
                }
            } else {                                           // v: M=token, N=ch
                int b = mb >> 12, t = mb & 4095;
                int kt = t >> 6, k64 = t & 63;
                int h = nc >> 6, d = nc & 63;
                size_t addr = ((((size_t)(b * 8 + h) * 64 + kt) * 64 + d) << 6) + k64;
                u16x4 w = { f2bf(acc[i][j][0]), f2bf(acc[i][j][1]),
                            f2bf(acc[i][j][2]), f2bf(acc[i][j][3]) };
                *(u16x4*)(&C[addr]) = w;
            }
        }
    }
}

// ---------- fused qk-proj + v-proj (r1-exact) ----------
__global__ __launch_bounds__(256) void k_qkv(const u16* __restrict__ Wqk_t, const float* __restrict__ cond,
                                             const float* __restrict__ x, const u16* __restrict__ Wv_t,
                                             u16* __restrict__ Qh, u16* __restrict__ Kh,
                                             u16* __restrict__ Vb) {
    __shared__ __align__(16) u16 smem[(128 + 128) * 72];
    u16* As = smem;
    u16* Bs = smem + 128 * 72;
    int bid = blockIdx.x;
    if (bid < 512) {
        int bx = bid >> 6, by = bid & 63;                  // 8 x 64
        gemm_body<u16, 1, false, true, 128, 128>(bx * 128, by * 128, Wqk_t, cond, nullptr, Qh, Kh, As, Bs);
    } else {
        int bid2 = bid - 512;                              // 256 blocks
        int by = bid2 >> 6, bx = bid2 & 63;                // 4 x 64
        gemm_body<u16, 2, true, false, 128, 128>(bx * 128, by * 128, x, Wv_t, nullptr, Vb, nullptr, As, Bs);
    }
}

// ---------- out proj (r1-exact) ----------
__global__ __launch_bounds__(256) void k_out(const u16* __restrict__ Wu_t, const u16* __restrict__ at,
                                             const float* __restrict__ bu, float* __restrict__ out) {
    __shared__ __align__(16) u16 smem[(128 + 128) * 72];
    int bid = blockIdx.x;
    int bx = bid >> 6, by = bid & 63;                      // 4 x 64
    gemm_body<float, 0, false, false, 128, 128>(bx * 128, by * 128, Wu_t, at, bu, out, nullptr,
                                                smem, smem + 128 * 72);
}

// ---------- flash: KVBLK=128 (16 iters, half the barriers), K+V XOR-swizzled stride-64 ----------
// Registers limit flash to 1 block/CU, so no co-resident block hides barrier drains;
// halving barrier count attacks the ~28% idle directly. LDS = 64 KiB exactly (free at 1 blk/CU).
// K LDS [128 kv][64 d], V LDS 2 sub-tiles [64 d][64 kv]; group g at g ^ s(row),
// s(row) = (row&3)|(((row>>3)&1)<<2). Read-side s: K rows kk*32+pi0(+4) -> l16&7;
// V rows c*16+l16 -> (l16&3)|(((l16>>3)&1)<<2). Both conflict-free (8 lanes/4-quad slot).
__global__ __launch_bounds__(512) void k_flash(const u16* __restrict__ Qh, const u16* __restrict__ Kh,
                                               const u16* __restrict__ Vb, u16* __restrict__ o) {
    int bid = blockIdx.x;
    int h = bid & 7, qt = (bid >> 3) & 31, b = bid >> 8;
    int tid = threadIdx.x;
    int wave = tid >> 6, lane = tid & 63, l16 = lane & 15, q = lane >> 4;
    int ks = wave >> 2, w4 = wave & 3;
    int t256 = tid & 255;

    __shared__ __align__(16) u16 smem[32768];              // 65536 B: 2ks x (K 8192 + V 8192)
    u16* Kt = smem + ks * 16384;
    u16* Vt = Kt + 8192;

    int head = b * 8 + h;
    short8 qf[2][2];
#pragma unroll
    for (int g = 0; g < 2; ++g) {
        const u16* qp = Qh + ((size_t)head * 4096 + qt * 128 + g * 64 + w4 * 16 + l16) * 64 + q * 8;
        qf[g][0] = *(const short8*)(qp);
        qf[g][1] = *(const short8*)(qp + 32);
    }

    const u16* kb = Kh + (size_t)head * 4096 * 64;
    const u16* vb = Vb + (size_t)head * 4096 * 64;

    int r0 = t256 >> 3, g0 = t256 & 7;
    int sr = (r0 & 3) | (((r0 >> 3) & 1) << 2);            // s(row) same for rows r0+32j
    u16* kw[4]; u16* vw[4];
#pragma unroll
    for (int j = 0; j < 4; ++j) {
        kw[j] = &Kt[(r0 + 32 * j) * 64 + ((g0 ^ sr) << 3)];
        vw[j] = &Vt[(j >> 1) * 4096 + (r0 + 32 * (j & 1)) * 64 + ((g0 ^ sr) << 3)];
    }

    f32x4 oacc[2][4];
#pragma unroll
    for (int g = 0; g < 2; ++g)
#pragma unroll
        for (int c = 0; c < 4; ++c) oacc[g][c] = (f32x4){0.f, 0.f, 0.f, 0.f};
    f32x4 lacc[2];
    lacc[0] = (f32x4){0.f, 0.f, 0.f, 0.f};
    lacc[1] = (f32x4){0.f, 0.f, 0.f, 0.f};
    const short8 ones = { 0x3F80, 0x3F80, 0x3F80, 0x3F80, 0x3F80, 0x3F80, 0x3F80, 0x3F80 };
    int pi0 = (l16 >> 2) * 8 + (l16 & 3);
    int sq = l16 & 7;                                      // K read-side swizzle
    int sv = (l16 & 3) | (((l16 >> 3) & 1) << 2);          // V read-side swizzle
    int st = qt & 15;                                      // rotation start (L2 spread)

    short8 rk[4], rv[4];
    size_t off0 = (size_t)(ks * 16 + st) * 8192;
#pragma unroll
    for (int j = 0; j < 4; ++j) {
        rk[j] = *(const short8*)(kb + off0 + j * 2048 + t256 * 8);
        rv[j] = *(const short8*)(vb + off0 + j * 2048 + t256 * 8);
    }

#pragma unroll 1
    for (int it = 0; it < 16; ++it) {
        __syncthreads();
#pragma unroll
        for (int j = 0; j < 4; ++j) { *(short8*)kw[j] = rk[j]; *(short8*)vw[j] = rv[j]; }
        __syncthreads();

        size_t offn = (size_t)(ks * 16 + ((st + it + 1) & 15)) * 8192;
#pragma unroll
        for (int j = 0; j < 4; ++j) {
            rk[j] = *(const short8*)(kb + offn + j * 2048 + t256 * 8);
            rv[j] = *(const short8*)(vb + offn + j * 2048 + t256 * 8);
        }
        __builtin_amdgcn_sched_barrier(0);

        __builtin_amdgcn_s_setprio(1);
#pragma unroll
        for (int kk = 0; kk < 4; ++kk) {
            const u16* ka = &Kt[(kk * 32 + pi0) * 64];
            short8 A00 = *(const short8*)(ka + ((q ^ sq) << 3));
            short8 A01 = *(const short8*)(ka + (((4 | q) ^ sq) << 3));
            short8 A10 = *(const short8*)(ka + 4 * 64 + ((q ^ sq) << 3));
            short8 A11 = *(const short8*)(ka + 4 * 64 + (((4 | q) ^ sq) << 3));
            const u16* va = &Vt[(kk >> 1) * 4096];
            int vg = (((kk & 1) * 4 + q) ^ sv) << 3;
            short8 vfc[4];
#pragma unroll
            for (int c = 0; c < 4; ++c)
                vfc[c] = *(const short8*)(va + (c * 16 + l16) * 64 + vg);

#pragma unroll
            for (int g = 0; g < 2; ++g) {
                f32x4 s0 = (f32x4){0.f, 0.f, 0.f, 0.f};
                f32x4 s1 = (f32x4){0.f, 0.f, 0.f, 0.f};
                s0 = mfma16(A00, qf[g][0], s0); s0 = mfma16(A01, qf[g][1], s0);
                s1 = mfma16(A10, qf[g][0], s1); s1 = mfma16(A11, qf[g][1], s1);

                uint4 pd;
                pd.x = __builtin_amdgcn_perm(rbits(__builtin_amdgcn_exp2f(s0[1])),
                                             rbits(__builtin_amdgcn_exp2f(s0[0])), 0x07060302u);
                pd.y = __builtin_amdgcn_perm(rbits(__builtin_amdgcn_exp2f(s0[3])),
                                             rbits(__builtin_amdgcn_exp2f(s0[2])), 0x07060302u);
                pd.z = __builtin_amdgcn_perm(rbits(__builtin_amdgcn_exp2f(s1[1])),
                                             rbits(__builtin_amdgcn_exp2f(s1[0])), 0x07060302u);
                pd.w = __builtin_amdgcn_perm(rbits(__builtin_amdgcn_exp2f(s1[3])),
                                             rbits(__builtin_amdgcn_exp2f(s1[2])), 0x07060302u);
                short8 pf;
                __builtin_memcpy(&pf, &pd, 16);

                lacc[g] = mfma16(ones, pf, lacc[g]);
#pragma unroll
                for (int c = 0; c < 4; ++c)
                    oacc[g][c] = mfma16(vfc[c], pf, oacc[g][c]);
            }
        }
        __builtin_amdgcn_s_setprio(0);
    }

    __syncthreads();
    float* red = (float*)smem;
    if (ks == 1) {
        float* rp = red + ((w4 * 64 + lane) * 37);
#pragma unroll
        for (int g = 0; g < 2; ++g)
#pragma unroll
            for (int c = 0; c < 4; ++c)
#pragma unroll
                for (int r = 0; r < 4; ++r) rp[g * 16 + c * 4 + r] = oacc[g][c][r];
        rp[32] = lacc[0][0];
        rp[33] = lacc[1][0];
    }
    __syncthreads();
    if (ks == 0) {
        const float* rp = red + ((w4 * 64 + lane) * 37);
#pragma unroll
        for (int g = 0; g < 2; ++g) {
#pragma unroll
            for (int c = 0; c < 4; ++c)
#pragma unroll
                for (int r = 0; r < 4; ++r) oacc[g][c][r] += rp[g * 16 + c * 4 + r];
            float inv = 1.f / (lacc[g][0] + rp[32 + g]);
            u16* ob = o + (size_t)(b * T_SZ + qt * 128 + g * 64 + w4 * 16 + l16) * 512 + h * 64 + q * 4;
#pragma unroll
            for (int c = 0; c < 4; ++c) {
                u16x4 w = { f2bf(oacc[g][c][0] * inv), f2bf(oacc[g][c][1] * inv),
                            f2bf(oacc[g][c][2] * inv), f2bf(oacc[g][c][3] * inv) };
                *(u16x4*)(ob + c * 16) = w;
            }
        }
    }
}

extern "C" void kernel_launch(void* const* d_in, const int* in_sizes, int n_in,
                              void* d_out, int out_size, void* d_ws, size_t ws_size,
                              hipStream_t stream) {
    const float* x    = (const float*)d_in[0];   // [2,4096,512] f32
    const float* cond = (const float*)d_in[1];   // [2,4096,512] f32
    const float* Wqk  = (const float*)d_in[2];   // [512,1024]   f32
    const float* Wv   = (const float*)d_in[3];   // [512,512]    f32
    const float* Wu   = (const float*)d_in[4];   // [512,512]    f32
    const float* bu   = (const float*)d_in[5];   // [512]        f32
    float* out = (float*)d_out;                  // [2,4096,512] f32

    const size_t MT = (size_t)B_SZ * T_SZ;       // 8192
    u16* qh_ws = (u16*)d_ws;                     // [16 heads,4096,64]  8 MB (Q pre-scaled)
    u16* kh_ws = qh_ws + MT * 512;               // [16 heads,4096,64]  8 MB
    u16* vb_ws = kh_ws + MT * 512;               // [16,64kt,64d,64k]   8 MB
    u16* at_ws = vb_ws + MT * 512;               // [8192,512]          8 MB
    u16* Wqk_t = at_ws + MT * 512;               // [1024,512]          1 MB
    u16* Wv_t  = Wqk_t + (size_t)1024 * 512;     // [512,512]         0.5 MB
    u16* Wu_t  = Wv_t + (size_t)512 * 512;       // [512,512]         0.5 MB

    k_prep<<<256, 256, 0, stream>>>(Wqk, Wv, Wu, Wqk_t, Wv_t, Wu_t);
    k_qkv<<<768, 256, 0, stream>>>(Wqk_t, cond, x, Wv_t, qh_ws, kh_ws, vb_ws);
    k_flash<<<512, 512, 0, stream>>>(qh_ws, kh_ws, vb_ws, at_ws);
    k_out<<<256, 256, 0, stream>>>(Wu_t, at_ws, bu, out);
}